// Round 1
// baseline (4525.244 us; speedup 1.0000x reference)
//
#include <hip/hip_runtime.h>
#include <math.h>

#define B_ 4096
#define N_ 32768
#define D_ 1024

#define BM 128
#define BN 128
#define KC 16
#define NCHUNK 32
#define CHUNK (N_ / NCHUNK)   // 1024 columns per chunk
#define TILES (CHUNK / BN)    // 8 tiles per chunk

// ---------------------------------------------------------------------------
// Kernel 1: inverse L2 norms for query rows and key rows.
// One block (256 threads) per row; row length 1024 = 256 float4 loads.
// Also zeroes the variance accumulator slot in d_out (re-poisoned each call).
// ---------------------------------------------------------------------------
__global__ __launch_bounds__(256) void norm_kernel(
    const float* __restrict__ q, const float* __restrict__ k,
    float* __restrict__ invq, float* __restrict__ invk,
    float* __restrict__ out)
{
    const int row = blockIdx.x;          // [0, B_+N_)
    const int t = threadIdx.x;

    const float* src;
    float* dst;
    if (row < B_) { src = q + (size_t)row * D_;          dst = invq + row; }
    else          { src = k + (size_t)(row - B_) * D_;   dst = invk + (row - B_); }

    float4 v = ((const float4*)src)[t];
    float s = v.x * v.x + v.y * v.y + v.z * v.z + v.w * v.w;

    #pragma unroll
    for (int off = 32; off > 0; off >>= 1)
        s += __shfl_down(s, off);

    __shared__ float red[4];
    if ((t & 63) == 0) red[t >> 6] = s;
    __syncthreads();
    if (t == 0) {
        float tot = red[0] + red[1] + red[2] + red[3];
        *dst = 1.0f / fmaxf(sqrtf(tot), 1e-12f);
        if (row == 0) out[(size_t)B_ * D_] = 0.0f;  // zero var accumulator
    }
}

// ---------------------------------------------------------------------------
// Kernel 2: fp32 sim GEMM with fused per-row streaming stats.
// Block: 256 threads (16x16), 128x128 tile, 8x8 per-thread micro-tile.
// LDS slabs stored k-major (transposed) so compute reads are float4.
// Each block covers one b-tile x one n-chunk (8 tiles of 128 columns);
// writes per-row partial {sum, sumsq, max, argmax} to workspace.
// ---------------------------------------------------------------------------
__global__ __launch_bounds__(256) void sim_stats_kernel(
    const float* __restrict__ q, const float* __restrict__ km,
    const float* __restrict__ invq, const float* __restrict__ invk,
    float* __restrict__ partials)
{
    __shared__ float qs[KC][BM + 4];   // +4 pad keeps float4 alignment (132*4=528B)
    __shared__ float ks[KC][BN + 4];
    __shared__ float sred[16][17][4];  // cross-thread stats staging

    const int tid = threadIdx.x;
    const int tx = tid & 15;
    const int ty = tid >> 4;
    const int chunk = blockIdx.x;      // 0..NCHUNK-1
    const int btile = blockIdx.y;      // 0..B_/BM-1

    const int lrow = tid >> 1;         // 0..127 (staging row)
    const int lhalf = tid & 1;         // which 8-float half of the KC=16 slab

    const int b0 = btile * BM;
    const int nbase = chunk * CHUNK;

    float inq[8];
    #pragma unroll
    for (int i = 0; i < 8; ++i) inq[i] = invq[b0 + ty * 8 + i];

    float sum[8], sumsq[8], mx[8];
    int amx[8];
    #pragma unroll
    for (int i = 0; i < 8; ++i) { sum[i] = 0.f; sumsq[i] = 0.f; mx[i] = -INFINITY; amx[i] = 0; }

    const size_t qbase = (size_t)(b0 + lrow) * D_ + lhalf * 8;

    for (int nt = 0; nt < TILES; ++nt) {
        const int n0 = nbase + nt * BN;
        const size_t kbase = (size_t)(n0 + lrow) * D_ + lhalf * 8;

        float acc[8][8];
        #pragma unroll
        for (int i = 0; i < 8; ++i)
            #pragma unroll
            for (int j = 0; j < 8; ++j) acc[i][j] = 0.f;

        // prefetch slab 0
        float4 aq0 = *(const float4*)(q + qbase);
        float4 aq1 = *(const float4*)(q + qbase + 4);
        float4 ak0 = *(const float4*)(km + kbase);
        float4 ak1 = *(const float4*)(km + kbase + 4);

        for (int kt = 0; kt < D_ / KC; ++kt) {
            __syncthreads();   // previous compute done before LDS overwrite
            // transpose-store: slab is [KC k's][128 rows]
            qs[lhalf * 8 + 0][lrow] = aq0.x; qs[lhalf * 8 + 1][lrow] = aq0.y;
            qs[lhalf * 8 + 2][lrow] = aq0.z; qs[lhalf * 8 + 3][lrow] = aq0.w;
            qs[lhalf * 8 + 4][lrow] = aq1.x; qs[lhalf * 8 + 5][lrow] = aq1.y;
            qs[lhalf * 8 + 6][lrow] = aq1.z; qs[lhalf * 8 + 7][lrow] = aq1.w;
            ks[lhalf * 8 + 0][lrow] = ak0.x; ks[lhalf * 8 + 1][lrow] = ak0.y;
            ks[lhalf * 8 + 2][lrow] = ak0.z; ks[lhalf * 8 + 3][lrow] = ak0.w;
            ks[lhalf * 8 + 4][lrow] = ak1.x; ks[lhalf * 8 + 5][lrow] = ak1.y;
            ks[lhalf * 8 + 6][lrow] = ak1.z; ks[lhalf * 8 + 7][lrow] = ak1.w;
            __syncthreads();

            if (kt + 1 < D_ / KC) {       // prefetch next slab during compute
                const size_t o = (size_t)(kt + 1) * KC;
                aq0 = *(const float4*)(q + qbase + o);
                aq1 = *(const float4*)(q + qbase + o + 4);
                ak0 = *(const float4*)(km + kbase + o);
                ak1 = *(const float4*)(km + kbase + o + 4);
            }

            #pragma unroll
            for (int k = 0; k < KC; ++k) {
                const float4 a0 = *(const float4*)&qs[k][ty * 8];
                const float4 a1 = *(const float4*)&qs[k][ty * 8 + 4];
                const float4 w0 = *(const float4*)&ks[k][tx * 8];
                const float4 w1 = *(const float4*)&ks[k][tx * 8 + 4];
                const float av[8] = {a0.x, a0.y, a0.z, a0.w, a1.x, a1.y, a1.z, a1.w};
                const float bw[8] = {w0.x, w0.y, w0.z, w0.w, w1.x, w1.y, w1.z, w1.w};
                #pragma unroll
                for (int i = 0; i < 8; ++i)
                    #pragma unroll
                    for (int j = 0; j < 8; ++j)
                        acc[i][j] = fmaf(av[i], bw[j], acc[i][j]);
            }
        }

        // fold this tile into running per-row stats (cols ascending => first-max kept)
        float inkv[8];
        #pragma unroll
        for (int j = 0; j < 8; ++j) inkv[j] = invk[n0 + tx * 8 + j];
        #pragma unroll
        for (int i = 0; i < 8; ++i) {
            #pragma unroll
            for (int j = 0; j < 8; ++j) {
                const float s = acc[i][j] * inq[i] * inkv[j];
                sum[i] += s;
                sumsq[i] = fmaf(s, s, sumsq[i]);
                if (s > mx[i]) { mx[i] = s; amx[i] = n0 + tx * 8 + j; }
            }
        }
    }

    // cross-thread (over tx) reduction, one row-slot i at a time
    #pragma unroll 1
    for (int i = 0; i < 8; ++i) {
        __syncthreads();
        sred[ty][tx][0] = sum[i];
        sred[ty][tx][1] = sumsq[i];
        sred[ty][tx][2] = mx[i];
        sred[ty][tx][3] = __int_as_float(amx[i]);
        __syncthreads();
        if (tid < 16) {
            float s = 0.f, q2 = 0.f, m = -INFINITY;
            int a = 0x7fffffff;
            for (int x = 0; x < 16; ++x) {
                const float vv = sred[tid][x][2];
                const int idx = __float_as_int(sred[tid][x][3]);
                s += sred[tid][x][0];
                q2 += sred[tid][x][1];
                if (vv > m || (vv == m && idx < a)) { m = vv; a = idx; }
            }
            const int row = b0 + tid * 8 + i;
            float* p = partials + ((size_t)row * NCHUNK + chunk) * 4;
            p[0] = s; p[1] = q2; p[2] = m; p[3] = __int_as_float(a);
        }
    }
}

// ---------------------------------------------------------------------------
// Kernel 3: per-row final reduce over chunks -> var contribution + gather.
// One block per query row.
// ---------------------------------------------------------------------------
__global__ __launch_bounds__(256) void finalize_kernel(
    const float* __restrict__ partials, const float* __restrict__ values,
    float* __restrict__ out)
{
    const int b = blockIdx.x;
    const int t = threadIdx.x;
    __shared__ int sbest;

    if (t == 0) {
        float s = 0.f, q2 = 0.f, m = -INFINITY;
        int a = 0x7fffffff;
        for (int c = 0; c < NCHUNK; ++c) {
            const float* p = partials + ((size_t)b * NCHUNK + c) * 4;
            s += p[0];
            q2 += p[1];
            const float vv = p[2];
            const int idx = __float_as_int(p[3]);
            if (vv > m || (vv == m && idx < a)) { m = vv; a = idx; }
        }
        const float var = (q2 - s * s / (float)N_) / (float)(N_ - 1);
        atomicAdd(out + (size_t)B_ * D_, var * (1.0f / B_));
        sbest = a;
    }
    __syncthreads();

    const int best = sbest;
    const float4 vv = *(const float4*)(values + (size_t)best * D_ + t * 4);
    *(float4*)(out + (size_t)b * D_ + t * 4) = vv;
}

// ---------------------------------------------------------------------------
extern "C" void kernel_launch(void* const* d_in, const int* in_sizes, int n_in,
                              void* d_out, int out_size, void* d_ws, size_t ws_size,
                              hipStream_t stream)
{
    const float* q = (const float*)d_in[0];   // [B, D]
    const float* k = (const float*)d_in[1];   // [N, D]
    const float* v = (const float*)d_in[2];   // [N, D]
    float* out = (float*)d_out;               // [B*D retrieved | 1 var]
    float* ws = (float*)d_ws;

    float* invq = ws;                  // B_ floats
    float* invk = ws + B_;             // N_ floats
    float* partials = ws + B_ + N_;    // B_ * NCHUNK * 4 floats (~2 MB)

    norm_kernel<<<B_ + N_, 256, 0, stream>>>(q, k, invq, invk, out);
    sim_stats_kernel<<<dim3(NCHUNK, B_ / BM), 256, 0, stream>>>(q, k, invq, invk, partials);
    finalize_kernel<<<B_, 256, 0, stream>>>(partials, v, out);
}

// Round 2
// 1376.177 us; speedup vs baseline: 3.2883x; 3.2883x over previous
//
#include <hip/hip_runtime.h>
#include <math.h>
#include <stdint.h>

#define B_ 4096
#define N_ 32768
#define D_ 1024

#define BM 128
#define BN 128
#define KS 32          // K per staging step (one mfma K)
#define NT 8           // n-tiles per block
#define NCHUNK 32      // N_/(BN*NT) chunk partials per row

typedef __attribute__((ext_vector_type(8))) short short8;
typedef __attribute__((ext_vector_type(4))) float f4;
typedef unsigned short u16;

__device__ __forceinline__ u16 bf16_rn(float x) {
    uint32_t u = __float_as_uint(x);
    u += 0x7fffu + ((u >> 16) & 1u);
    return (u16)(u >> 16);
}

// fp32 -> (hi, lo) bf16 pair, both round-to-nearest. Dropped residual ~2^-18 |x|.
__device__ __forceinline__ void split4(f4 v, uint2& hpack, uint2& lpack) {
    u16 h[4], l[4];
    #pragma unroll
    for (int e = 0; e < 4; ++e) {
        float x = v[e];
        u16 hb = bf16_rn(x);
        float hf = __uint_as_float(((uint32_t)hb) << 16);
        h[e] = hb;
        l[e] = bf16_rn(x - hf);
    }
    hpack.x = (uint32_t)h[0] | ((uint32_t)h[1] << 16);
    hpack.y = (uint32_t)h[2] | ((uint32_t)h[3] << 16);
    lpack.x = (uint32_t)l[0] | ((uint32_t)l[1] << 16);
    lpack.y = (uint32_t)l[2] | ((uint32_t)l[3] << 16);
}

// ---------------------------------------------------------------------------
// Kernel 1: inverse L2 norms; also zeroes the var accumulator slot in d_out.
// ---------------------------------------------------------------------------
__global__ __launch_bounds__(256) void norm_kernel(
    const float* __restrict__ q, const float* __restrict__ k,
    float* __restrict__ invq, float* __restrict__ invk,
    float* __restrict__ out)
{
    const int row = blockIdx.x;
    const int t = threadIdx.x;

    const float* src;
    float* dst;
    if (row < B_) { src = q + (size_t)row * D_;          dst = invq + row; }
    else          { src = k + (size_t)(row - B_) * D_;   dst = invk + (row - B_); }

    float4 v = ((const float4*)src)[t];
    float s = v.x * v.x + v.y * v.y + v.z * v.z + v.w * v.w;

    #pragma unroll
    for (int off = 32; off > 0; off >>= 1)
        s += __shfl_down(s, off);

    __shared__ float red[4];
    if ((t & 63) == 0) red[t >> 6] = s;
    __syncthreads();
    if (t == 0) {
        float tot = red[0] + red[1] + red[2] + red[3];
        *dst = 1.0f / fmaxf(sqrtf(tot), 1e-12f);
        if (row == 0) out[(size_t)B_ * D_] = 0.0f;
    }
}

// ---------------------------------------------------------------------------
// Kernel 2: split-bf16 MFMA sim GEMM with fused streaming per-row stats.
// 128x128 tile, 4 waves (2x2), 64x64 per wave via 4x4 mfma_f32_16x16x32_bf16.
// 3 MFMA per frag pair: hi*hi + hi*lo + lo*hi (lo*lo dropped, ~1e-7 sim err).
// Per-row {sum, sumsq, top1, top2} streamed; partials per (row, chunk).
// ---------------------------------------------------------------------------
__global__ __launch_bounds__(256, 2) void sim_stats_kernel(
    const float* __restrict__ qg, const float* __restrict__ kg,
    const float* __restrict__ invq, const float* __restrict__ invk,
    float* __restrict__ partials)
{
    __shared__ __align__(16) char smem[33536];   // staging (32KB) aliased w/ scan (33.3KB)
    __shared__ float invq_s[BM];
    __shared__ float invk_s[BN];

    u16 (*qhi)[KS] = (u16(*)[KS])(smem);
    u16 (*qlo)[KS] = (u16(*)[KS])(smem + 8192);
    u16 (*khi)[KS] = (u16(*)[KS])(smem + 16384);
    u16 (*klo)[KS] = (u16(*)[KS])(smem + 24576);
    float (*scan)[65] = (float(*)[65])(smem);    // [128][64+1] pad breaks bank stride

    const int tid = threadIdx.x;
    const int lane = tid & 63;
    const int w = tid >> 6;
    const int wm = w >> 1, wn = w & 1;           // wave 2x2 grid over 128x128
    const int quad = lane >> 4;
    const int l16 = lane & 15;
    const int mtile = blockIdx.x;                // x fastest => co-resident blocks share k-chunk (L2 reuse)
    const int chunk = blockIdx.y;
    const int b0 = mtile * BM;
    const int srow = tid >> 3;                   // staging: 8 float4 per row of 32 floats
    const int sf = tid & 7;

    if (tid < BM) invq_s[tid] = invq[b0 + tid];

    float r_sum = 0.f, r_sq = 0.f, r_m1 = -INFINITY, r_m2 = -INFINITY;
    int r_i1 = 0x7fffffff, r_i2 = 0x7fffffff;

    const f4 zf = {0.f, 0.f, 0.f, 0.f};

    for (int nt = 0; nt < NT; ++nt) {
        const int n0 = chunk * (BN * NT) + nt * BN;
        __syncthreads();                          // prior tile's scan reads done
        if (tid < BN) invk_s[tid] = invk[n0 + tid];

        f4 acc[4][4];
        #pragma unroll
        for (int i = 0; i < 4; ++i)
            #pragma unroll
            for (int j = 0; j < 4; ++j) acc[i][j] = zf;

        f4 pq[4], pk[4];
        #pragma unroll
        for (int rr = 0; rr < 4; ++rr) {
            pq[rr] = *(const f4*)(qg + (size_t)(b0 + srow + 32*rr) * D_ + sf*4);
            pk[rr] = *(const f4*)(kg + (size_t)(n0 + srow + 32*rr) * D_ + sf*4);
        }

        for (int kt = 0; kt < D_ / KS; ++kt) {
            __syncthreads();                      // prior frag reads done before overwrite
            #pragma unroll
            for (int rr = 0; rr < 4; ++rr) {
                uint2 hp, lp;
                split4(pq[rr], hp, lp);
                *(uint2*)&qhi[srow + 32*rr][sf*4] = hp;
                *(uint2*)&qlo[srow + 32*rr][sf*4] = lp;
                split4(pk[rr], hp, lp);
                *(uint2*)&khi[srow + 32*rr][sf*4] = hp;
                *(uint2*)&klo[srow + 32*rr][sf*4] = lp;
            }
            __syncthreads();
            if (kt + 1 < D_ / KS) {               // prefetch next slab during compute
                const int ko = (kt + 1) * KS;
                #pragma unroll
                for (int rr = 0; rr < 4; ++rr) {
                    pq[rr] = *(const f4*)(qg + (size_t)(b0 + srow + 32*rr) * D_ + ko + sf*4);
                    pk[rr] = *(const f4*)(kg + (size_t)(n0 + srow + 32*rr) * D_ + ko + sf*4);
                }
            }
            // A layout: m=lane&15, k=quad*8+j (k-contiguous rows => sequential b128)
            short8 ah[4], al[4];
            #pragma unroll
            for (int i = 0; i < 4; ++i) {
                ah[i] = *(const short8*)&qhi[wm*64 + i*16 + l16][quad*8];
                al[i] = *(const short8*)&qlo[wm*64 + i*16 + l16][quad*8];
            }
            #pragma unroll
            for (int j = 0; j < 4; ++j) {
                short8 bh = *(const short8*)&khi[wn*64 + j*16 + l16][quad*8];
                short8 bl = *(const short8*)&klo[wn*64 + j*16 + l16][quad*8];
                #pragma unroll
                for (int i = 0; i < 4; ++i) {
                    acc[i][j] = __builtin_amdgcn_mfma_f32_16x16x32_bf16(ah[i], bh, acc[i][j], 0, 0, 0);
                    acc[i][j] = __builtin_amdgcn_mfma_f32_16x16x32_bf16(ah[i], bl, acc[i][j], 0, 0, 0);
                    acc[i][j] = __builtin_amdgcn_mfma_f32_16x16x32_bf16(al[i], bh, acc[i][j], 0, 0, 0);
                }
            }
        }

        // epilogue: dump raw acc -> LDS in two 64-col halves, scalar-scan rows.
        const int srrow = tid >> 1;
        const float myinq = invq_s[srrow];
        #pragma unroll 1
        for (int h = 0; h < 2; ++h) {
            __syncthreads();
            if (wn == h) {
                #pragma unroll
                for (int i = 0; i < 4; ++i)
                    #pragma unroll
                    for (int j = 0; j < 4; ++j)
                        #pragma unroll
                        for (int p = 0; p < 4; ++p)
                            scan[wm*64 + i*16 + quad*4 + p][j*16 + l16] = acc[i][j][p];
            }
            __syncthreads();
            #pragma unroll 1
            for (int ii = 0; ii < 32; ++ii) {
                const int c = (tid & 1) * 32 + ii;
                const float sv = scan[srrow][c] * myinq * invk_s[h*64 + c];
                const int gi = n0 + h*64 + c;
                r_sum += sv;
                r_sq = fmaf(sv, sv, r_sq);
                if (sv > r_m1)      { r_m2 = r_m1; r_i2 = r_i1; r_m1 = sv; r_i1 = gi; }
                else if (sv > r_m2) { r_m2 = sv; r_i2 = gi; }
            }
        }
    }

    // merge even/odd thread (same row, disjoint cols), write chunk partials
    __syncthreads();
    float* mb = (float*)smem;
    mb[tid*6+0] = r_sum; mb[tid*6+1] = r_sq;
    mb[tid*6+2] = r_m1;  mb[tid*6+3] = __int_as_float(r_i1);
    mb[tid*6+4] = r_m2;  mb[tid*6+5] = __int_as_float(r_i2);
    __syncthreads();
    if ((tid & 1) == 0) {
        const float* o = mb + (size_t)(tid + 1) * 6;
        const float bs = o[0], bq = o[1], bm1 = o[2], bm2 = o[4];
        const int bi1 = __float_as_int(o[3]), bi2 = __float_as_int(o[5]);
        float s = r_sum + bs, q2 = r_sq + bq;
        float m1 = r_m1, m2 = r_m2; int i1 = r_i1, i2 = r_i2;
        if (bm1 > m1 || (bm1 == m1 && bi1 < i1)) {
            float nm2; int ni2;
            if (m1 > bm2 || (m1 == bm2 && i1 < bi2)) { nm2 = m1; ni2 = i1; }
            else                                     { nm2 = bm2; ni2 = bi2; }
            m1 = bm1; i1 = bi1; m2 = nm2; i2 = ni2;
        } else if (bm1 > m2 || (bm1 == m2 && bi1 < i2)) {
            m2 = bm1; i2 = bi1;
        }
        const int row = b0 + (tid >> 1);
        float* p = partials + ((size_t)row * NCHUNK + chunk) * 8;
        f4 p0 = {s, q2, m1, __int_as_float(i1)};
        f4 p1 = {m2, __int_as_float(i2), 0.f, 0.f};
        *(f4*)p = p0;
        *(f4*)(p + 4) = p1;
    }
}

// ---------------------------------------------------------------------------
// Kernel 3: per-row merge of chunk partials; fp64 exact rescue of top-2;
// var accumulation; gather values[winner]. One wave per row.
// ---------------------------------------------------------------------------
__global__ __launch_bounds__(64) void finalize_kernel(
    const float* __restrict__ partials,
    const float* __restrict__ qg, const float* __restrict__ kg,
    const float* __restrict__ values,
    const float* __restrict__ invq, const float* __restrict__ invk,
    float* __restrict__ out)
{
    const int b = blockIdx.x;
    const int lane = threadIdx.x;

    float s = 0.f, q2 = 0.f, m1 = -INFINITY, m2 = -INFINITY;
    int i1 = 0x7fffffff, i2 = 0x7fffffff;
    if (lane < NCHUNK) {
        const float* p = partials + ((size_t)b * NCHUNK + lane) * 8;
        s = p[0]; q2 = p[1]; m1 = p[2]; i1 = __float_as_int(p[3]);
        m2 = p[4]; i2 = __float_as_int(p[5]);
    }
    #pragma unroll
    for (int msk = 1; msk < 64; msk <<= 1) {
        const float bs = __shfl_xor(s, msk), bq = __shfl_xor(q2, msk);
        const float bm1 = __shfl_xor(m1, msk), bm2 = __shfl_xor(m2, msk);
        const int bi1 = __shfl_xor(i1, msk), bi2 = __shfl_xor(i2, msk);
        s += bs; q2 += bq;
        if (bm1 > m1 || (bm1 == m1 && bi1 < i1)) {
            float nm2; int ni2;
            if (m1 > bm2 || (m1 == bm2 && i1 < bi2)) { nm2 = m1; ni2 = i1; }
            else                                     { nm2 = bm2; ni2 = bi2; }
            m1 = bm1; i1 = bi1; m2 = nm2; i2 = ni2;
        } else if (bm1 > m2 || (bm1 == m2 && bi1 < i2)) {
            m2 = bm1; i2 = bi1;
        }
    }
    if (lane == 0) {
        const float var = (q2 - s * s / (float)N_) / (float)(N_ - 1);
        atomicAdd(out + (size_t)B_ * D_, var * (1.0f / B_));
    }

    // exact fp64 recompute of both candidates (always; deterministic)
    const float* qrow = qg + (size_t)b * D_;
    const float* k1 = kg + (size_t)i1 * D_;
    const float* k2 = kg + (size_t)i2 * D_;
    double d1 = 0.0, d2 = 0.0;
    #pragma unroll
    for (int v4 = 0; v4 < 4; ++v4) {
        const int off = v4 * 256 + lane * 4;
        const f4 qv = *(const f4*)(qrow + off);
        const f4 a1 = *(const f4*)(k1 + off);
        const f4 a2 = *(const f4*)(k2 + off);
        #pragma unroll
        for (int e = 0; e < 4; ++e) {
            d1 += (double)qv[e] * (double)a1[e];
            d2 += (double)qv[e] * (double)a2[e];
        }
    }
    #pragma unroll
    for (int msk = 1; msk < 64; msk <<= 1) {
        d1 += __shfl_xor(d1, msk);
        d2 += __shfl_xor(d2, msk);
    }
    const double sc = (double)invq[b];
    const double s1 = d1 * sc * (double)invk[i1];
    const double s2 = d2 * sc * (double)invk[i2];
    const int winner = (s2 > s1 || (s2 == s1 && i2 < i1)) ? i2 : i1;

    const float* vrow = values + (size_t)winner * D_;
    float* orow = out + (size_t)b * D_;
    #pragma unroll
    for (int v4 = 0; v4 < 4; ++v4) {
        const int off = v4 * 256 + lane * 4;
        *(f4*)(orow + off) = *(const f4*)(vrow + off);
    }
}

// ---------------------------------------------------------------------------
extern "C" void kernel_launch(void* const* d_in, const int* in_sizes, int n_in,
                              void* d_out, int out_size, void* d_ws, size_t ws_size,
                              hipStream_t stream)
{
    const float* q = (const float*)d_in[0];   // [B, D]
    const float* k = (const float*)d_in[1];   // [N, D]
    const float* v = (const float*)d_in[2];   // [N, D]
    float* out = (float*)d_out;               // [B*D retrieved | 1 var]
    float* ws = (float*)d_ws;

    float* invq = ws;                          // B_ floats
    float* invk = ws + B_;                     // N_ floats
    float* partials = ws + B_ + N_;            // B_ * NCHUNK * 8 floats (~4 MB)

    norm_kernel<<<B_ + N_, 256, 0, stream>>>(q, k, invq, invk, out);
    sim_stats_kernel<<<dim3(B_ / BM, NCHUNK), 256, 0, stream>>>(q, k, invq, invk, partials);
    finalize_kernel<<<B_, 64, 0, stream>>>(partials, q, k, v, invq, invk, out);
}

// Round 3
// 1195.081 us; speedup vs baseline: 3.7866x; 1.1515x over previous
//
#include <hip/hip_runtime.h>
#include <math.h>
#include <stdint.h>

#define B_ 4096
#define N_ 32768
#define D_ 1024

#define BM 128
#define BN 128
#define NT 2
#define NCHUNK 128     // N_ / (BN*NT)

typedef __attribute__((ext_vector_type(8))) short short8;
typedef __attribute__((ext_vector_type(4))) float f4;
typedef unsigned short u16;

__device__ __forceinline__ u16 bf16_rn(float x) {
    uint32_t u = __float_as_uint(x);
    u += 0x7fffu + ((u >> 16) & 1u);
    return (u16)(u >> 16);
}

// fp32 -> (hi, lo) bf16 pair, both RN. Dropped residual ~2^-18 |x|.
__device__ __forceinline__ void split4(f4 v, uint2& hpack, uint2& lpack) {
    u16 h[4], l[4];
    #pragma unroll
    for (int e = 0; e < 4; ++e) {
        float x = v[e];
        u16 hb = bf16_rn(x);
        float hf = __uint_as_float(((uint32_t)hb) << 16);
        h[e] = hb;
        l[e] = bf16_rn(x - hf);
    }
    hpack.x = (uint32_t)h[0] | ((uint32_t)h[1] << 16);
    hpack.y = (uint32_t)h[2] | ((uint32_t)h[3] << 16);
    lpack.x = (uint32_t)l[0] | ((uint32_t)l[1] << 16);
    lpack.y = (uint32_t)l[2] | ((uint32_t)l[3] << 16);
}

// async global -> LDS, 16B per lane. LDS dest is wave-uniform base + lane*16.
__device__ __forceinline__ void g2l16(const void* g, void* l) {
    __builtin_amdgcn_global_load_lds(
        (const __attribute__((address_space(1))) char*)(uintptr_t)g,
        (__attribute__((address_space(3))) char*)(uint32_t)(uintptr_t)l,
        16, 0, 0);
}

// ---------------------------------------------------------------------------
// Kernel 1: inverse L2 norms; zeroes the var accumulator slot in d_out.
// ---------------------------------------------------------------------------
__global__ __launch_bounds__(256) void norm_kernel(
    const float* __restrict__ q, const float* __restrict__ k,
    float* __restrict__ invq, float* __restrict__ invk,
    float* __restrict__ out)
{
    const int row = blockIdx.x;
    const int t = threadIdx.x;

    const float* src;
    float* dst;
    if (row < B_) { src = q + (size_t)row * D_;          dst = invq + row; }
    else          { src = k + (size_t)(row - B_) * D_;   dst = invk + (row - B_); }

    float4 v = ((const float4*)src)[t];
    float s = v.x * v.x + v.y * v.y + v.z * v.z + v.w * v.w;

    #pragma unroll
    for (int off = 32; off > 0; off >>= 1)
        s += __shfl_down(s, off);

    __shared__ float red[4];
    if ((t & 63) == 0) red[t >> 6] = s;
    __syncthreads();
    if (t == 0) {
        float tot = red[0] + red[1] + red[2] + red[3];
        *dst = 1.0f / fmaxf(sqrtf(tot), 1e-12f);
        if (row == 0) out[(size_t)B_ * D_] = 0.0f;
    }
}

// ---------------------------------------------------------------------------
// Kernel 2: pre-normalize + split into bf16 hi/lo planes (row-major [row][D]).
// One block per row; 4 elements per thread.
// ---------------------------------------------------------------------------
__global__ __launch_bounds__(256) void split_kernel(
    const float* __restrict__ q, const float* __restrict__ k,
    const float* __restrict__ invq, const float* __restrict__ invk,
    u16* __restrict__ qhi, u16* __restrict__ qlo,
    u16* __restrict__ khi, u16* __restrict__ klo)
{
    const int row = blockIdx.x;
    const int t = threadIdx.x;

    const float* src;
    float scale;
    u16 *dhi, *dlo;
    if (row < B_) {
        src = q + (size_t)row * D_; scale = invq[row];
        dhi = qhi + (size_t)row * D_; dlo = qlo + (size_t)row * D_;
    } else {
        const int r = row - B_;
        src = k + (size_t)r * D_; scale = invk[r];
        dhi = khi + (size_t)r * D_; dlo = klo + (size_t)r * D_;
    }

    f4 v = ((const f4*)src)[t];
    v *= scale;
    uint2 hp, lp;
    split4(v, hp, lp);
    ((uint2*)dhi)[t] = hp;
    ((uint2*)dlo)[t] = lp;
}

// ---------------------------------------------------------------------------
// Kernel 3: split-bf16 MFMA sim GEMM, operands pre-normalized & pre-split.
// Staging: each wave DMAs one 8KB plane (qhi/qlo/khi/klo) per K=32 slab via
// global_load_lds (no VALU conversion). 128x128 tile, 4 waves, 64x64/wave,
// 3 MFMA per frag pair (hi*hi + hi*lo + lo*hi). acc == sim directly.
// ---------------------------------------------------------------------------
__global__ __launch_bounds__(256) void sim_stats_kernel(
    const u16* __restrict__ qhi, const u16* __restrict__ qlo,
    const u16* __restrict__ khi, const u16* __restrict__ klo,
    float* __restrict__ partials)
{
    __shared__ __align__(16) char smem[34816];   // staging 32KB | scan [128][68]f

    const int tid = threadIdx.x;
    const int lane = tid & 63;
    const int w = tid >> 6;
    const int wm = w >> 1, wn = w & 1;
    const int quad = lane >> 4;
    const int l16 = lane & 15;
    const int mtile = blockIdx.x;                // fastest => k-slab shared in L2
    const int chunk = blockIdx.y;
    const int b0 = mtile * BM;

    const u16* sbase = (w == 0) ? qhi : (w == 1) ? qlo : (w == 2) ? khi : klo;
    char* ldsreg = smem + w * 8192;
    const int lofs = (lane >> 2) * D_ + (lane & 3) * 8;   // per-lane source offset (elems)

    const u16 (*qh)[32] = (const u16(*)[32])(smem);
    const u16 (*ql)[32] = (const u16(*)[32])(smem + 8192);
    const u16 (*kh)[32] = (const u16(*)[32])(smem + 16384);
    const u16 (*kl)[32] = (const u16(*)[32])(smem + 24576);
    float (*scan)[68] = (float(*)[68])smem;

    float r_sum = 0.f, r_sq = 0.f, r_m1 = -INFINITY, r_m2 = -INFINITY;
    int r_i1 = 0x7fffffff, r_i2 = 0x7fffffff;

    const f4 zf = {0.f, 0.f, 0.f, 0.f};

    for (int nt = 0; nt < NT; ++nt) {
        const int n0 = chunk * (BN * NT) + nt * BN;
        const int rowbase = (w < 2) ? b0 : n0;
        const u16* wsrc = sbase + (size_t)rowbase * D_ + lofs;

        f4 acc[4][4];
        #pragma unroll
        for (int i = 0; i < 4; ++i)
            #pragma unroll
            for (int j = 0; j < 4; ++j) acc[i][j] = zf;

        for (int kt = 0; kt < D_ / 32; ++kt) {
            __syncthreads();                      // prior slab consumers done
            const u16* sp = wsrc + kt * 32;
            #pragma unroll
            for (int t = 0; t < 8; ++t)
                g2l16(sp + (size_t)t * 16 * D_, ldsreg + t * 1024);
            __syncthreads();                      // DMA drained (vmcnt before barrier)

            short8 ah[4], al[4];
            #pragma unroll
            for (int i = 0; i < 4; ++i) {
                ah[i] = *(const short8*)&qh[wm*64 + i*16 + l16][quad*8];
                al[i] = *(const short8*)&ql[wm*64 + i*16 + l16][quad*8];
            }
            #pragma unroll
            for (int j = 0; j < 4; ++j) {
                short8 bh = *(const short8*)&kh[wn*64 + j*16 + l16][quad*8];
                short8 bl = *(const short8*)&kl[wn*64 + j*16 + l16][quad*8];
                #pragma unroll
                for (int i = 0; i < 4; ++i) {
                    acc[i][j] = __builtin_amdgcn_mfma_f32_16x16x32_bf16(ah[i], bh, acc[i][j], 0, 0, 0);
                    acc[i][j] = __builtin_amdgcn_mfma_f32_16x16x32_bf16(ah[i], bl, acc[i][j], 0, 0, 0);
                    acc[i][j] = __builtin_amdgcn_mfma_f32_16x16x32_bf16(al[i], bh, acc[i][j], 0, 0, 0);
                }
            }
        }

        // epilogue: dump raw acc (== sim) to LDS in two 64-col halves, scan rows
        const int srow = tid >> 1;
        const int c0 = (tid & 1) * 32;
        #pragma unroll 1
        for (int h = 0; h < 2; ++h) {
            __syncthreads();
            if (wn == h) {
                #pragma unroll
                for (int i = 0; i < 4; ++i)
                    #pragma unroll
                    for (int j = 0; j < 4; ++j)
                        #pragma unroll
                        for (int p = 0; p < 4; ++p)
                            scan[wm*64 + i*16 + quad*4 + p][j*16 + l16] = acc[i][j][p];
            }
            __syncthreads();
            const int gbase = n0 + h * 64 + c0;
            #pragma unroll
            for (int u = 0; u < 8; ++u) {
                const f4 v = *(const f4*)&scan[srow][c0 + 4*u];
                #pragma unroll
                for (int e = 0; e < 4; ++e) {
                    const float sv = v[e];
                    const int gi = gbase + 4*u + e;
                    r_sum += sv;
                    r_sq = fmaf(sv, sv, r_sq);
                    if (sv > r_m1)      { r_m2 = r_m1; r_i2 = r_i1; r_m1 = sv; r_i1 = gi; }
                    else if (sv > r_m2) { r_m2 = sv; r_i2 = gi; }
                }
            }
        }
    }

    // merge even/odd thread (same row, disjoint cols), write chunk partials
    __syncthreads();
    float* mb = (float*)smem;
    mb[tid*6+0] = r_sum; mb[tid*6+1] = r_sq;
    mb[tid*6+2] = r_m1;  mb[tid*6+3] = __int_as_float(r_i1);
    mb[tid*6+4] = r_m2;  mb[tid*6+5] = __int_as_float(r_i2);
    __syncthreads();
    if ((tid & 1) == 0) {
        const float* o = mb + (size_t)(tid + 1) * 6;
        const float bs = o[0], bq = o[1], bm1 = o[2], bm2 = o[4];
        const int bi1 = __float_as_int(o[3]), bi2 = __float_as_int(o[5]);
        float s = r_sum + bs, q2 = r_sq + bq;
        float m1 = r_m1, m2 = r_m2; int i1 = r_i1, i2 = r_i2;
        if (bm1 > m1 || (bm1 == m1 && bi1 < i1)) {
            float nm2; int ni2;
            if (m1 > bm2 || (m1 == bm2 && i1 < bi2)) { nm2 = m1; ni2 = i1; }
            else                                     { nm2 = bm2; ni2 = bi2; }
            m1 = bm1; i1 = bi1; m2 = nm2; i2 = ni2;
        } else if (bm1 > m2 || (bm1 == m2 && bi1 < i2)) {
            m2 = bm1; i2 = bi1;
        }
        const int row = b0 + (tid >> 1);
        float* p = partials + ((size_t)row * NCHUNK + chunk) * 8;
        f4 p0 = {s, q2, m1, __int_as_float(i1)};
        f4 p1 = {m2, __int_as_float(i2), 0.f, 0.f};
        *(f4*)p = p0;
        *(f4*)(p + 4) = p1;
    }
}

// ---------------------------------------------------------------------------
// Kernel 4: per-row merge of chunk partials; fp64 exact rescue of top-2;
// var accumulation; gather values[winner]. One wave per row.
// ---------------------------------------------------------------------------
__global__ __launch_bounds__(64) void finalize_kernel(
    const float* __restrict__ partials,
    const float* __restrict__ qg, const float* __restrict__ kg,
    const float* __restrict__ values,
    const float* __restrict__ invq, const float* __restrict__ invk,
    float* __restrict__ out)
{
    const int b = blockIdx.x;
    const int lane = threadIdx.x;

    float s = 0.f, q2 = 0.f, m1 = -INFINITY, m2 = -INFINITY;
    int i1 = 0x7fffffff, i2 = 0x7fffffff;
    #pragma unroll
    for (int cc = 0; cc < NCHUNK / 64; ++cc) {
        const int c = lane + cc * 64;
        const float* p = partials + ((size_t)b * NCHUNK + c) * 8;
        const float bs = p[0], bq = p[1], bm1 = p[2], bm2 = p[4];
        const int bi1 = __float_as_int(p[3]), bi2 = __float_as_int(p[5]);
        s += bs; q2 += bq;
        if (bm1 > m1 || (bm1 == m1 && bi1 < i1)) {
            float nm2; int ni2;
            if (m1 > bm2 || (m1 == bm2 && i1 < bi2)) { nm2 = m1; ni2 = i1; }
            else                                     { nm2 = bm2; ni2 = bi2; }
            m1 = bm1; i1 = bi1; m2 = nm2; i2 = ni2;
        } else if (bm1 > m2 || (bm1 == m2 && bi1 < i2)) {
            m2 = bm1; i2 = bi1;
        }
    }
    #pragma unroll
    for (int msk = 1; msk < 64; msk <<= 1) {
        const float bs = __shfl_xor(s, msk), bq = __shfl_xor(q2, msk);
        const float bm1 = __shfl_xor(m1, msk), bm2 = __shfl_xor(m2, msk);
        const int bi1 = __shfl_xor(i1, msk), bi2 = __shfl_xor(i2, msk);
        s += bs; q2 += bq;
        if (bm1 > m1 || (bm1 == m1 && bi1 < i1)) {
            float nm2; int ni2;
            if (m1 > bm2 || (m1 == bm2 && i1 < bi2)) { nm2 = m1; ni2 = i1; }
            else                                     { nm2 = bm2; ni2 = bi2; }
            m1 = bm1; i1 = bi1; m2 = nm2; i2 = ni2;
        } else if (bm1 > m2 || (bm1 == m2 && bi1 < i2)) {
            m2 = bm1; i2 = bi1;
        }
    }
    if (lane == 0) {
        const float var = (q2 - s * s / (float)N_) / (float)(N_ - 1);
        atomicAdd(out + (size_t)B_ * D_, var * (1.0f / B_));
    }

    // exact fp64 recompute of both candidates (deterministic tie-break)
    const float* qrow = qg + (size_t)b * D_;
    const float* k1 = kg + (size_t)i1 * D_;
    const float* k2 = kg + (size_t)i2 * D_;
    double d1 = 0.0, d2 = 0.0;
    #pragma unroll
    for (int v4 = 0; v4 < 4; ++v4) {
        const int off = v4 * 256 + lane * 4;
        const f4 qv = *(const f4*)(qrow + off);
        const f4 a1 = *(const f4*)(k1 + off);
        const f4 a2 = *(const f4*)(k2 + off);
        #pragma unroll
        for (int e = 0; e < 4; ++e) {
            d1 += (double)qv[e] * (double)a1[e];
            d2 += (double)qv[e] * (double)a2[e];
        }
    }
    #pragma unroll
    for (int msk = 1; msk < 64; msk <<= 1) {
        d1 += __shfl_xor(d1, msk);
        d2 += __shfl_xor(d2, msk);
    }
    const double sc = (double)invq[b];
    const double s1 = d1 * sc * (double)invk[i1];
    const double s2 = d2 * sc * (double)invk[i2];
    const int winner = (s2 > s1 || (s2 == s1 && i2 < i1)) ? i2 : i1;

    const float* vrow = values + (size_t)winner * D_;
    float* orow = out + (size_t)b * D_;
    #pragma unroll
    for (int v4 = 0; v4 < 4; ++v4) {
        const int off = v4 * 256 + lane * 4;
        *(f4*)(orow + off) = *(const f4*)(vrow + off);
    }
}

// ---------------------------------------------------------------------------
extern "C" void kernel_launch(void* const* d_in, const int* in_sizes, int n_in,
                              void* d_out, int out_size, void* d_ws, size_t ws_size,
                              hipStream_t stream)
{
    const float* q = (const float*)d_in[0];   // [B, D]
    const float* k = (const float*)d_in[1];   // [N, D]
    const float* v = (const float*)d_in[2];   // [N, D]
    float* out = (float*)d_out;               // [B*D retrieved | 1 var]
    float* ws = (float*)d_ws;

    float* invq = ws;                                          // 4096 f
    float* invk = ws + B_;                                     // 32768 f
    float* partials = ws + B_ + N_;                            // 4096*128*8 f (16 MB)
    u16* qhi = (u16*)(partials + (size_t)B_ * NCHUNK * 8);     // 8 MB
    u16* qlo = qhi + (size_t)B_ * D_;                          // 8 MB
    u16* khi = qlo + (size_t)B_ * D_;                          // 64 MB
    u16* klo = khi + (size_t)N_ * D_;                          // 64 MB

    norm_kernel<<<B_ + N_, 256, 0, stream>>>(q, k, invq, invk, out);
    split_kernel<<<B_ + N_, 256, 0, stream>>>(q, k, invq, invk, qhi, qlo, khi, klo);
    sim_stats_kernel<<<dim3(B_ / BM, NCHUNK), 256, 0, stream>>>(qhi, qlo, khi, klo, partials);
    finalize_kernel<<<B_, 64, 0, stream>>>(partials, q, k, v, invq, invk, out);
}

// Round 4
// 1019.254 us; speedup vs baseline: 4.4398x; 1.1725x over previous
//
#include <hip/hip_runtime.h>
#include <math.h>
#include <stdint.h>

#define B_ 4096
#define N_ 32768
#define D_ 1024

#define BM 128
#define BN 128
#define NT 2
#define NCHUNK 128     // N_ / (BN*NT)
#define KTOT 32        // D_ / 32

typedef __attribute__((ext_vector_type(8))) short short8;
typedef __attribute__((ext_vector_type(4))) float f4;
typedef unsigned short u16;

__device__ __forceinline__ u16 bf16_rn(float x) {
    uint32_t u = __float_as_uint(x);
    u += 0x7fffu + ((u >> 16) & 1u);
    return (u16)(u >> 16);
}

// fp32 -> (hi, lo) bf16 pair, both RN. Dropped residual ~2^-18 |x|.
__device__ __forceinline__ void split4(f4 v, uint2& hpack, uint2& lpack) {
    u16 h[4], l[4];
    #pragma unroll
    for (int e = 0; e < 4; ++e) {
        float x = v[e];
        u16 hb = bf16_rn(x);
        float hf = __uint_as_float(((uint32_t)hb) << 16);
        h[e] = hb;
        l[e] = bf16_rn(x - hf);
    }
    hpack.x = (uint32_t)h[0] | ((uint32_t)h[1] << 16);
    hpack.y = (uint32_t)h[2] | ((uint32_t)h[3] << 16);
    lpack.x = (uint32_t)l[0] | ((uint32_t)l[1] << 16);
    lpack.y = (uint32_t)l[2] | ((uint32_t)l[3] << 16);
}

// async global -> LDS, 16B per lane. LDS dest is wave-uniform base + lane*16.
__device__ __forceinline__ void g2l16(const void* g, void* l) {
    __builtin_amdgcn_global_load_lds(
        (const __attribute__((address_space(1))) char*)(uintptr_t)g,
        (__attribute__((address_space(3))) char*)(uint32_t)(uintptr_t)l,
        16, 0, 0);
}

// ---------------------------------------------------------------------------
// Kernel 1: inverse L2 norms; zeroes the var accumulator slot in d_out.
// ---------------------------------------------------------------------------
__global__ __launch_bounds__(256) void norm_kernel(
    const float* __restrict__ q, const float* __restrict__ k,
    float* __restrict__ invq, float* __restrict__ invk,
    float* __restrict__ out)
{
    const int row = blockIdx.x;
    const int t = threadIdx.x;

    const float* src;
    float* dst;
    if (row < B_) { src = q + (size_t)row * D_;          dst = invq + row; }
    else          { src = k + (size_t)(row - B_) * D_;   dst = invk + (row - B_); }

    float4 v = ((const float4*)src)[t];
    float s = v.x * v.x + v.y * v.y + v.z * v.z + v.w * v.w;

    #pragma unroll
    for (int off = 32; off > 0; off >>= 1)
        s += __shfl_down(s, off);

    __shared__ float red[4];
    if ((t & 63) == 0) red[t >> 6] = s;
    __syncthreads();
    if (t == 0) {
        float tot = red[0] + red[1] + red[2] + red[3];
        *dst = 1.0f / fmaxf(sqrtf(tot), 1e-12f);
        if (row == 0) out[(size_t)B_ * D_] = 0.0f;
    }
}

// ---------------------------------------------------------------------------
// Kernel 2: normalize + split into bf16 hi/lo planes, packed FRAG-LINEAR:
// chunk(kt, g) = 1KB covering rows 16g..16g+15, k = 32kt..32kt+31, stored in
// MFMA lane order: lane l holds (m = l&15, k = (l>>4)*8 + 0..7), 16B/lane.
// Plane layout: [kt][group][512 u16].
// One block per 16-row group; wave w handles kts w, w+4, ...
// ---------------------------------------------------------------------------
__global__ __launch_bounds__(256) void split_pack_kernel(
    const float* __restrict__ q, const float* __restrict__ k,
    const float* __restrict__ invq, const float* __restrict__ invk,
    u16* __restrict__ qhi, u16* __restrict__ qlo,
    u16* __restrict__ khi, u16* __restrict__ klo)
{
    const int g = blockIdx.x;                 // 0..(B_+N_)/16-1
    const int lane = threadIdx.x & 63;
    const int w = threadIdx.x >> 6;

    const float* src; const float* inv;
    u16 *dhi, *dlo; int groups, gg;
    if (g < B_ / 16) { src = q; inv = invq; dhi = qhi; dlo = qlo; groups = B_ / 16; gg = g; }
    else { src = k; inv = invk; dhi = khi; dlo = klo; groups = N_ / 16; gg = g - B_ / 16; }

    const int row = gg * 16 + (lane & 15);
    const float scale = inv[row];
    const int kofs = (lane >> 4) * 8;
    const float* rp = src + (size_t)row * D_;

    #pragma unroll 1
    for (int kt = w; kt < KTOT; kt += 4) {
        f4 v0 = *(const f4*)(rp + kt * 32 + kofs);
        f4 v1 = *(const f4*)(rp + kt * 32 + kofs + 4);
        v0 *= scale; v1 *= scale;
        uint2 h0, l0, h1, l1;
        split4(v0, h0, l0);
        split4(v1, h1, l1);
        const size_t cbase = ((size_t)kt * groups + gg) * 512 + lane * 8;
        uint4 hh = {h0.x, h0.y, h1.x, h1.y};
        uint4 ll = {l0.x, l0.y, l1.x, l1.y};
        *(uint4*)(dhi + cbase) = hh;
        *(uint4*)(dlo + cbase) = ll;
    }
}

// ---------------------------------------------------------------------------
// Kernel 3: split-bf16 MFMA sim GEMM over frag-linear packed operands.
// Double-buffered LDS (2 x 32KB): iter kt drains DMAs issued at kt-1 (full
// compute-iteration in flight), then issues kt+1. Frag reads are sequential
// (base + lane*16): zero bank conflicts. 3 MFMA per frag pair.
// ---------------------------------------------------------------------------
__global__ __launch_bounds__(256) void sim_stats_kernel(
    const u16* __restrict__ qhi, const u16* __restrict__ qlo,
    const u16* __restrict__ khi, const u16* __restrict__ klo,
    float* __restrict__ partials)
{
    __shared__ __align__(16) char smem[65536];   // 2 x 32KB slabs; scan aliased

    const int tid = threadIdx.x;
    const int lane = tid & 63;
    const int w = tid >> 6;
    const int wm = w >> 1, wn = w & 1;
    const int quad = lane >> 4;
    const int l16 = lane & 15;
    const int mtile = blockIdx.x;
    const int chunk = blockIdx.y;
    const int b0 = mtile * BM;

    const u16* sbase = (w == 0) ? qhi : (w == 1) ? qlo : (w == 2) ? khi : klo;
    const int groups = (w < 2) ? (B_ / 16) : (N_ / 16);

    float (*scan)[68] = (float(*)[68])smem;

    float r_sum = 0.f, r_sq = 0.f, r_m1 = -INFINITY, r_m2 = -INFINITY;
    int r_i1 = 0x7fffffff, r_i2 = 0x7fffffff;

    const f4 zf = {0.f, 0.f, 0.f, 0.f};

    for (int nt = 0; nt < NT; ++nt) {
        const int n0 = chunk * (BN * NT) + nt * BN;
        const int g0 = ((w < 2) ? b0 : n0) >> 4;

        __syncthreads();                      // scan reads of prev tile done
        // prologue: DMA slab kt=0 -> buf0
        {
            const size_t cb = ((size_t)0 * groups + g0) * 512 + lane * 8;
            char* dst = smem + w * 8192;
            #pragma unroll
            for (int t = 0; t < 8; ++t)
                g2l16(sbase + cb + t * 512, dst + t * 1024);
        }

        f4 acc[4][4];
        #pragma unroll
        for (int i = 0; i < 4; ++i)
            #pragma unroll
            for (int j = 0; j < 4; ++j) acc[i][j] = zf;

        for (int kt = 0; kt < KTOT; ++kt) {
            const int cur = kt & 1;
            __syncthreads();                  // drains vmcnt(0): buf[cur] complete
            if (kt + 1 < KTOT) {              // issue kt+1 -> buf[1-cur]
                const size_t cb = ((size_t)(kt + 1) * groups + g0) * 512 + lane * 8;
                char* dst = smem + (1 - cur) * 32768 + w * 8192;
                #pragma unroll
                for (int t = 0; t < 8; ++t)
                    g2l16(sbase + cb + t * 512, dst + t * 1024);
            }
            const char* cbuf = smem + cur * 32768;

            short8 ah[4], al[4];
            #pragma unroll
            for (int i = 0; i < 4; ++i) {
                ah[i] = *(const short8*)(cbuf + (wm * 4 + i) * 1024 + lane * 16);
                al[i] = *(const short8*)(cbuf + 8192 + (wm * 4 + i) * 1024 + lane * 16);
            }
            #pragma unroll
            for (int j = 0; j < 4; ++j) {
                short8 bh = *(const short8*)(cbuf + 16384 + (wn * 4 + j) * 1024 + lane * 16);
                short8 bl = *(const short8*)(cbuf + 24576 + (wn * 4 + j) * 1024 + lane * 16);
                #pragma unroll
                for (int i = 0; i < 4; ++i) {
                    acc[i][j] = __builtin_amdgcn_mfma_f32_16x16x32_bf16(ah[i], bh, acc[i][j], 0, 0, 0);
                    acc[i][j] = __builtin_amdgcn_mfma_f32_16x16x32_bf16(ah[i], bl, acc[i][j], 0, 0, 0);
                    acc[i][j] = __builtin_amdgcn_mfma_f32_16x16x32_bf16(al[i], bh, acc[i][j], 0, 0, 0);
                }
            }
        }

        // epilogue: dump raw acc (== sim) to LDS in two 64-col halves, scan rows
        const int srow = tid >> 1;
        const int c0 = (tid & 1) * 32;
        #pragma unroll 1
        for (int h = 0; h < 2; ++h) {
            __syncthreads();
            if (wn == h) {
                #pragma unroll
                for (int i = 0; i < 4; ++i)
                    #pragma unroll
                    for (int j = 0; j < 4; ++j)
                        #pragma unroll
                        for (int p = 0; p < 4; ++p)
                            scan[wm*64 + i*16 + quad*4 + p][j*16 + l16] = acc[i][j][p];
            }
            __syncthreads();
            const int gbase = n0 + h * 64 + c0;
            #pragma unroll
            for (int u = 0; u < 8; ++u) {
                const f4 v = *(const f4*)&scan[srow][c0 + 4*u];
                #pragma unroll
                for (int e = 0; e < 4; ++e) {
                    const float sv = v[e];
                    const int gi = gbase + 4*u + e;
                    r_sum += sv;
                    r_sq = fmaf(sv, sv, r_sq);
                    if (sv > r_m1)      { r_m2 = r_m1; r_i2 = r_i1; r_m1 = sv; r_i1 = gi; }
                    else if (sv > r_m2) { r_m2 = sv; r_i2 = gi; }
                }
            }
        }
    }

    // merge even/odd thread (same row, disjoint cols), write chunk partials
    __syncthreads();
    float* mb = (float*)smem;
    mb[tid*6+0] = r_sum; mb[tid*6+1] = r_sq;
    mb[tid*6+2] = r_m1;  mb[tid*6+3] = __int_as_float(r_i1);
    mb[tid*6+4] = r_m2;  mb[tid*6+5] = __int_as_float(r_i2);
    __syncthreads();
    if ((tid & 1) == 0) {
        const float* o = mb + (size_t)(tid + 1) * 6;
        const float bs = o[0], bq = o[1], bm1 = o[2], bm2 = o[4];
        const int bi1 = __float_as_int(o[3]), bi2 = __float_as_int(o[5]);
        float s = r_sum + bs, q2 = r_sq + bq;
        float m1 = r_m1, m2 = r_m2; int i1 = r_i1, i2 = r_i2;
        if (bm1 > m1 || (bm1 == m1 && bi1 < i1)) {
            float nm2; int ni2;
            if (m1 > bm2 || (m1 == bm2 && i1 < bi2)) { nm2 = m1; ni2 = i1; }
            else                                     { nm2 = bm2; ni2 = bi2; }
            m1 = bm1; i1 = bi1; m2 = nm2; i2 = ni2;
        } else if (bm1 > m2 || (bm1 == m2 && bi1 < i2)) {
            m2 = bm1; i2 = bi1;
        }
        const int row = b0 + (tid >> 1);
        float* p = partials + ((size_t)row * NCHUNK + chunk) * 8;
        f4 p0 = {s, q2, m1, __int_as_float(i1)};
        f4 p1 = {m2, __int_as_float(i2), 0.f, 0.f};
        *(f4*)p = p0;
        *(f4*)(p + 4) = p1;
    }
}

// ---------------------------------------------------------------------------
// Kernel 4: per-row merge of chunk partials; fp64 exact rescue of top-2;
// var accumulation; gather values[winner]. One wave per row.
// ---------------------------------------------------------------------------
__global__ __launch_bounds__(64) void finalize_kernel(
    const float* __restrict__ partials,
    const float* __restrict__ qg, const float* __restrict__ kg,
    const float* __restrict__ values,
    const float* __restrict__ invq, const float* __restrict__ invk,
    float* __restrict__ out)
{
    const int b = blockIdx.x;
    const int lane = threadIdx.x;

    float s = 0.f, q2 = 0.f, m1 = -INFINITY, m2 = -INFINITY;
    int i1 = 0x7fffffff, i2 = 0x7fffffff;
    #pragma unroll
    for (int cc = 0; cc < NCHUNK / 64; ++cc) {
        const int c = lane + cc * 64;
        const float* p = partials + ((size_t)b * NCHUNK + c) * 8;
        const float bs = p[0], bq = p[1], bm1 = p[2], bm2 = p[4];
        const int bi1 = __float_as_int(p[3]), bi2 = __float_as_int(p[5]);
        s += bs; q2 += bq;
        if (bm1 > m1 || (bm1 == m1 && bi1 < i1)) {
            float nm2; int ni2;
            if (m1 > bm2 || (m1 == bm2 && i1 < bi2)) { nm2 = m1; ni2 = i1; }
            else                                     { nm2 = bm2; ni2 = bi2; }
            m1 = bm1; i1 = bi1; m2 = nm2; i2 = ni2;
        } else if (bm1 > m2 || (bm1 == m2 && bi1 < i2)) {
            m2 = bm1; i2 = bi1;
        }
    }
    #pragma unroll
    for (int msk = 1; msk < 64; msk <<= 1) {
        const float bs = __shfl_xor(s, msk), bq = __shfl_xor(q2, msk);
        const float bm1 = __shfl_xor(m1, msk), bm2 = __shfl_xor(m2, msk);
        const int bi1 = __shfl_xor(i1, msk), bi2 = __shfl_xor(i2, msk);
        s += bs; q2 += bq;
        if (bm1 > m1 || (bm1 == m1 && bi1 < i1)) {
            float nm2; int ni2;
            if (m1 > bm2 || (m1 == bm2 && i1 < bi2)) { nm2 = m1; ni2 = i1; }
            else                                     { nm2 = bm2; ni2 = bi2; }
            m1 = bm1; i1 = bi1; m2 = nm2; i2 = ni2;
        } else if (bm1 > m2 || (bm1 == m2 && bi1 < i2)) {
            m2 = bm1; i2 = bi1;
        }
    }
    if (lane == 0) {
        const float var = (q2 - s * s / (float)N_) / (float)(N_ - 1);
        atomicAdd(out + (size_t)B_ * D_, var * (1.0f / B_));
    }

    // exact fp64 recompute of both candidates (deterministic tie-break)
    const float* qrow = qg + (size_t)b * D_;
    const float* k1 = kg + (size_t)i1 * D_;
    const float* k2 = kg + (size_t)i2 * D_;
    double d1 = 0.0, d2 = 0.0;
    #pragma unroll
    for (int v4 = 0; v4 < 4; ++v4) {
        const int off = v4 * 256 + lane * 4;
        const f4 qv = *(const f4*)(qrow + off);
        const f4 a1 = *(const f4*)(k1 + off);
        const f4 a2 = *(const f4*)(k2 + off);
        #pragma unroll
        for (int e = 0; e < 4; ++e) {
            d1 += (double)qv[e] * (double)a1[e];
            d2 += (double)qv[e] * (double)a2[e];
        }
    }
    #pragma unroll
    for (int msk = 1; msk < 64; msk <<= 1) {
        d1 += __shfl_xor(d1, msk);
        d2 += __shfl_xor(d2, msk);
    }
    const double sc = (double)invq[b];
    const double s1 = d1 * sc * (double)invk[i1];
    const double s2 = d2 * sc * (double)invk[i2];
    const int winner = (s2 > s1 || (s2 == s1 && i2 < i1)) ? i2 : i1;

    const float* vrow = values + (size_t)winner * D_;
    float* orow = out + (size_t)b * D_;
    #pragma unroll
    for (int v4 = 0; v4 < 4; ++v4) {
        const int off = v4 * 256 + lane * 4;
        *(f4*)(orow + off) = *(const f4*)(vrow + off);
    }
}

// ---------------------------------------------------------------------------
extern "C" void kernel_launch(void* const* d_in, const int* in_sizes, int n_in,
                              void* d_out, int out_size, void* d_ws, size_t ws_size,
                              hipStream_t stream)
{
    const float* q = (const float*)d_in[0];   // [B, D]
    const float* k = (const float*)d_in[1];   // [N, D]
    const float* v = (const float*)d_in[2];   // [N, D]
    float* out = (float*)d_out;               // [B*D retrieved | 1 var]
    float* ws = (float*)d_ws;

    float* invq = ws;                                          // 4096 f
    float* invk = ws + B_;                                     // 32768 f
    float* partials = ws + B_ + N_;                            // 4096*128*8 f (16 MB)
    u16* qhi = (u16*)(partials + (size_t)B_ * NCHUNK * 8);     // 8 MB packed
    u16* qlo = qhi + (size_t)B_ * D_;                          // 8 MB
    u16* khi = qlo + (size_t)B_ * D_;                          // 64 MB
    u16* klo = khi + (size_t)N_ * D_;                          // 64 MB

    norm_kernel<<<B_ + N_, 256, 0, stream>>>(q, k, invq, invk, out);
    split_pack_kernel<<<(B_ + N_) / 16, 256, 0, stream>>>(q, k, invq, invk, qhi, qlo, khi, klo);
    sim_stats_kernel<<<dim3(B_ / BM, NCHUNK), 256, 0, stream>>>(qhi, qlo, khi, klo, partials);
    finalize_kernel<<<B_, 64, 0, stream>>>(partials, q, k, v, invq, invk, out);
}